// Round 5
// baseline (268.360 us; speedup 1.0000x reference)
//
#include <hip/hip_runtime.h>

typedef unsigned int u32;
typedef unsigned short u16;

#define TPB 640

namespace {
// packed-path ws layout (float offsets)
constexpr size_t F_WP1  = 0;         // bf16[12][1280][160] LN-folded W1 (img80++txt80)
constexpr size_t F_WP2  = 1228800;   // bf16[12][80][1280]  W2 (img768++txt512)
constexpr size_t F_S1   = 1843200;   // f32 [12][160] colsum(W1g)
constexpr size_t F_T1   = 1845120;   // f32 [12][160] b·W1 + b1
constexpr size_t F_XI_P = 1847040;   // f32 [12][36][768]
constexpr size_t F_XT_P = 2178816;   // f32 [12][36][512]
constexpr size_t F_CI_P = 2400000;   // f32 [36][768] (padded start)
constexpr size_t F_CT_P = 2427648;   // f32 [36][512]
constexpr size_t F_END_P = 2446080;
// fallback (f32 weights read in place) ws layout
constexpr size_t F_XI_U = 0;
constexpr size_t F_XT_U = 331776;
constexpr size_t F_CI_U = 552960;
constexpr size_t F_CT_U = 580608;
}

__device__ __forceinline__ float bflo(u32 u) { return __uint_as_float(u << 16); }
__device__ __forceinline__ float bfhi(u32 u) { return __uint_as_float(u & 0xffff0000u); }
__device__ __forceinline__ float gelu_f(float x) { return 0.5f * x * (1.0f + erff(x * 0.70710678118654752f)); }
__device__ __forceinline__ u16 f2bf(float f) {
    u32 u = __float_as_uint(f);
    u += 0x7fffu + ((u >> 16) & 1u);
    return (u16)(u >> 16);
}

struct P {
    const float *vpc, *vpm, *tpc, *tpm, *cpc, *cpi, *cpt;
    const float *lig, *lib, *ltg, *ltb;
    const float *iw1, *ib1, *iw2, *ib2;
    const float *tw1, *tb1, *tw2, *tb2;
    const float *ciw1, *cib1, *ciw2, *cib2;
    const float *ctw1, *ctb1, *ctw2, *ctb2;
    const u16 *wp1, *wp2;              // packed bf16 weights
    const float *s1, *t1;              // folded LN colsums
    float *xi, *xt, *cimg, *ctxt;
};

// Blocks 0..23: fold+pack W1 (block = d*2+path), compute S1/T1.
// Blocks 24+ : pack W2 pairs.
__global__ __launch_bounds__(320) void prep_kernel(P p, u16* wp1o, u32* wp2o, float* s1o, float* t1o) {
    __shared__ float sA[4][80], sB[4][80];
    const int t = threadIdx.x;
    if (blockIdx.x < 24) {
        const int d = blockIdx.x >> 1, path = blockIdx.x & 1;
        const float* W1 = (path ? p.tw1 : p.iw1) + (size_t)d * 1280 * 80;
        const float* G  = (path ? p.ltg : p.lig) + d * 1280;
        const float* Bb = (path ? p.ltb : p.lib) + d * 1280;
        const int j = t % 80, kc = t / 80;       // 4 chunks of 320
        float S = 0.f, T = 0.f;
        for (int k = kc * 320; k < kc * 320 + 320; ++k) {
            float w = W1[(size_t)k * 80 + j];
            float wg = G[k] * w;
            S += wg; T += Bb[k] * w;
            wp1o[((size_t)(d * 1280) + k) * 160 + path * 80 + j] = f2bf(wg);
        }
        sA[kc][j] = S; sB[kc][j] = T;
        __syncthreads();
        if (t < 80) {
            float Ssum = sA[0][t] + sA[1][t] + sA[2][t] + sA[3][t];
            float Tsum = sB[0][t] + sB[1][t] + sB[2][t] + sB[3][t];
            s1o[d * 160 + path * 80 + t] = Ssum;
            t1o[d * 160 + path * 80 + t] = Tsum + (path ? p.tb1 : p.ib1)[d * 80 + t];
        }
    } else {
        constexpr u32 N2 = 12u * 80 * 640;       // u32 pairs of WP2
        u32 i = (blockIdx.x - 24) * 320 + t;
        if (i >= N2) return;
        u32 c2 = i % 640, rem = i / 640;
        u32 k = rem % 80, d = rem / 80;
        u32 c0 = 2 * c2;
        const float* s = (c0 < 768) ? (p.iw2 + ((size_t)(d * 80) + k) * 768 + c0)
                                    : (p.tw2 + ((size_t)(d * 80) + k) * 512 + (c0 - 768));
        float2 v = *reinterpret_cast<const float2*>(s);
        wp2o[i] = (u32)f2bf(v.x) | ((u32)f2bf(v.y) << 16);
    }
}

// Packed chain: blocks 0..35 one (variant, token) row; 36..71 common MLPs.
__global__ __launch_bounds__(TPB) void chain2_kernel(P p) {
    __shared__ float smem[6608];
    float* sx   = smem;           // [1280] raw x
    float* part = smem + 1280;    // [32][160] / reused as part2[2][1280]
    float* hh   = smem + 6400;    // [160]
    float* redA = smem + 6560;    // [10]
    float* redB = smem + 6580;    // [10]
    float* st   = smem + 6600;    // [2]

    const int tid = threadIdx.x;
    const int blk = blockIdx.x;

    if (blk < 36) {
        const int v = blk / 12, t = blk % 12;
        const float* is = (v == 2) ? p.vpm : p.vpc;
        const float* ts = (v == 1) ? p.tpm : p.tpc;
        for (int k = tid; k < 768; k += TPB) sx[k] = is[t * 768 + k];
        if (tid < 512) sx[768 + tid] = ts[t * 512 + tid];
        __syncthreads();

        for (int d = 0; d < 12; ++d) {
            // ---- LN stats over raw x ----
            {
                float x0 = sx[tid], x1 = sx[tid + 640];
                float s = x0 + x1, s2 = x0 * x0 + x1 * x1;
                #pragma unroll
                for (int off = 32; off > 0; off >>= 1) { s += __shfl_down(s, off); s2 += __shfl_down(s2, off); }
                if ((tid & 63) == 0) { redA[tid >> 6] = s; redB[tid >> 6] = s2; }
            }
            __syncthreads();
            if (tid == 0) {
                float S = 0.f, S2 = 0.f;
                #pragma unroll
                for (int w = 0; w < 10; ++w) { S += redA[w]; S2 += redB[w]; }
                float m = S * (1.0f / 1280.0f);
                float var = S2 * (1.0f / 1280.0f) - m * m;
                st[0] = m; st[1] = rsqrtf(var + 1e-5f);
            }
            // ---- GEMV1 on raw x: 8 cols x K-chunk-40 per thread ----
            {
                const int g = tid % 20, kc = tid / 20;    // 32 chunks
                const int j0 = 8 * g, k0 = 40 * kc;
                const u16* wp = p.wp1 + ((size_t)(d * 1280) + k0) * 160 + j0;
                float a0 = 0.f, a1 = 0.f, a2 = 0.f, a3 = 0.f;
                float a4 = 0.f, a5 = 0.f, a6 = 0.f, a7 = 0.f;
                #pragma unroll 8
                for (int i = 0; i < 40; ++i) {
                    uint4 w = *reinterpret_cast<const uint4*>(wp);
                    float xv = sx[k0 + i];
                    a0 += xv * bflo(w.x); a1 += xv * bfhi(w.x);
                    a2 += xv * bflo(w.y); a3 += xv * bfhi(w.y);
                    a4 += xv * bflo(w.z); a5 += xv * bfhi(w.z);
                    a6 += xv * bflo(w.w); a7 += xv * bfhi(w.w);
                    wp += 160;
                }
                *reinterpret_cast<float4*>(part + kc * 160 + j0)     = make_float4(a0, a1, a2, a3);
                *reinterpret_cast<float4*>(part + kc * 160 + j0 + 4) = make_float4(a4, a5, a6, a7);
            }
            __syncthreads();
            if (tid < 160) {
                float y = 0.f;
                #pragma unroll
                for (int kc = 0; kc < 32; ++kc) y += part[kc * 160 + tid];
                const float m = st[0], rs = st[1];
                float hpre = rs * y - m * rs * p.s1[d * 160 + tid] + p.t1[d * 160 + tid];
                hh[tid] = gelu_f(hpre);
            }
            __syncthreads();
            // ---- GEMV2: 4 cols x K-chunk-40 per thread ----
            {
                const int g2 = tid % 320, kc = tid / 320;  // 2 chunks
                const int c0 = 4 * g2, k0 = 40 * kc;
                const u16* wq = p.wp2 + ((size_t)(d * 80) + k0) * 1280 + c0;
                const float* hb = hh + ((c0 >= 768) ? 80 : 0);
                float a0 = 0.f, a1 = 0.f, a2 = 0.f, a3 = 0.f;
                #pragma unroll 8
                for (int i = 0; i < 40; ++i) {
                    uint2 w = *reinterpret_cast<const uint2*>(wq);
                    float hv = hb[k0 + i];
                    a0 += hv * bflo(w.x); a1 += hv * bfhi(w.x);
                    a2 += hv * bflo(w.y); a3 += hv * bfhi(w.y);
                    wq += 1280;
                }
                *reinterpret_cast<float4*>(part + kc * 1280 + c0) = make_float4(a0, a1, a2, a3);
            }
            __syncthreads();
            // ---- combine + write x(d+1) ----
            {
                const int c0 = 2 * tid;
                const int pth = (c0 >= 768);
                const int cc = c0 - 768 * pth;
                const int Np = pth ? 512 : 768;
                float2 bb = *reinterpret_cast<const float2*>((pth ? p.tb2 : p.ib2) + d * Np + cc);
                float a0 = part[c0]     + part[1280 + c0]     + bb.x;
                float a1 = part[c0 + 1] + part[1280 + c0 + 1] + bb.y;
                __syncthreads();   // part fully read before sx overwrite? (sx/part disjoint; this orders next-depth stats vs part) 
                sx[c0] = a0; sx[c0 + 1] = a1;
                float* xo = pth ? (p.xt + ((size_t)(d * 36) + blk) * 512 + cc)
                                : (p.xi + ((size_t)(d * 36) + blk) * 768 + cc);
                *reinterpret_cast<float2*>(xo) = make_float2(a0, a1);
            }
            __syncthreads();
        }
    } else {
        // ---- common-prompt MLPs ----
        float* cx  = smem;         // [512]
        float* ph  = smem + 512;   // [4][64]
        float* hhl = smem + 768;   // [64]
        const int rr = blk - 36, v = rr / 12, t = rr % 12;
        const float* cs = (v == 0) ? p.cpc : (v == 1) ? p.cpi : p.cpt;
        if (tid < 512) cx[tid] = cs[t * 512 + tid];
        __syncthreads();
        if (tid < 256) {
            const int o = tid & 63, kc = tid >> 6;
            const int path = o >> 5, j = o & 31;
            const float* w = (path ? p.ctw1 : p.ciw1) + (size_t)(kc * 128) * 32 + j;
            float a = 0.f;
            #pragma unroll 8
            for (int i = 0; i < 128; ++i) { a += cx[kc * 128 + i] * (*w); w += 32; }
            ph[kc * 64 + o] = a;
        }
        __syncthreads();
        if (tid < 64) {
            const int path = tid >> 5, j = tid & 31;
            float a = (path ? p.ctb1 : p.cib1)[j];
            #pragma unroll
            for (int kc = 0; kc < 4; ++kc) a += ph[kc * 64 + tid];
            hhl[tid] = gelu_f(a);
        }
        __syncthreads();
        for (int o = tid; o < 1280; o += TPB) {
            if (o < 768) {
                float a = p.cib2[o];
                #pragma unroll
                for (int k = 0; k < 32; ++k) a += hhl[k] * p.ciw2[k * 768 + o];
                p.cimg[rr * 768 + o] = a;
            } else {
                const int oo = o - 768;
                float a = p.ctb2[oo];
                #pragma unroll
                for (int k = 0; k < 32; ++k) a += hhl[32 + k] * p.ctw2[k * 512 + oo];
                p.ctxt[rr * 512 + oo] = a;
            }
        }
    }
}

// Fallback: f32 weights read in place (round-4 structure, known-good).
__global__ __launch_bounds__(TPB) void chain_fb_kernel(P p) {
    __shared__ float smem[6592];
    float* sx   = smem;
    float* xln0 = smem + 1280;
    float* xln1 = smem + 2560;
    float* part = smem + 3840;   // [16][160]
    float* hh   = smem + 6400;
    float* redA = smem + 6560;
    float* redB = smem + 6570;
    float* st   = smem + 6580;

    const int tid = threadIdx.x;
    const int blk = blockIdx.x;

    if (blk < 36) {
        const int v = blk / 12, t = blk % 12;
        const float* is = (v == 2) ? p.vpm : p.vpc;
        const float* ts = (v == 1) ? p.tpm : p.tpc;
        if (tid < 512) sx[768 + tid] = ts[t * 512 + tid];
        for (int k = tid; k < 768; k += TPB) sx[k] = is[t * 768 + k];
        __syncthreads();
        for (int d = 0; d < 12; ++d) {
            {
                float x0 = sx[tid], x1 = sx[tid + 640];
                float s = x0 + x1, s2 = x0 * x0 + x1 * x1;
                #pragma unroll
                for (int off = 32; off > 0; off >>= 1) { s += __shfl_down(s, off); s2 += __shfl_down(s2, off); }
                if ((tid & 63) == 0) { redA[tid >> 6] = s; redB[tid >> 6] = s2; }
            }
            __syncthreads();
            if (tid == 0) {
                float S = 0.f, S2 = 0.f;
                #pragma unroll
                for (int w = 0; w < 10; ++w) { S += redA[w]; S2 += redB[w]; }
                float m = S * (1.0f / 1280.0f);
                float var = S2 * (1.0f / 1280.0f) - m * m;
                st[0] = m; st[1] = rsqrtf(var + 1e-5f);
            }
            __syncthreads();
            const float m = st[0], rs = st[1];
            #pragma unroll
            for (int q = 0; q < 2; ++q) {
                const int k = tid + 640 * q;
                float xc = (sx[k] - m) * rs;
                xln0[k] = xc * p.lig[d * 1280 + k] + p.lib[d * 1280 + k];
                xln1[k] = xc * p.ltg[d * 1280 + k] + p.ltb[d * 1280 + k];
            }
            __syncthreads();
            {
                const int g = tid % 40, kc = tid / 40;
                const int j0 = 4 * g;
                const float* xl = (j0 >= 80) ? xln1 : xln0;
                const int k0 = kc * 80;
                float a0 = 0.f, a1 = 0.f, a2 = 0.f, a3 = 0.f;
                const float* wp = (j0 < 80) ? (p.iw1 + ((size_t)(d * 1280) + k0) * 80 + j0)
                                            : (p.tw1 + ((size_t)(d * 1280) + k0) * 80 + (j0 - 80));
                #pragma unroll 8
                for (int i = 0; i < 80; ++i) {
                    float4 w = *reinterpret_cast<const float4*>(wp);
                    float xv = xl[k0 + i];
                    a0 += xv * w.x; a1 += xv * w.y; a2 += xv * w.z; a3 += xv * w.w;
                    wp += 80;
                }
                *reinterpret_cast<float4*>(part + kc * 160 + j0) = make_float4(a0, a1, a2, a3);
            }
            __syncthreads();
            if (tid < 160) {
                const int path = tid >= 80, j = tid - 80 * path;
                float a = (path ? p.tb1 : p.ib1)[d * 80 + j];
                #pragma unroll
                for (int kc = 0; kc < 16; ++kc) a += part[kc * 160 + tid];
                hh[tid] = gelu_f(a);
            }
            __syncthreads();
            {
                const int c = tid;
                const int pth = (c >= 384);
                const int cc = 2 * c - 768 * pth;
                const float* hb = hh + 80 * pth;
                const int Np = pth ? 512 : 768;
                const float* b2 = (pth ? p.tb2 : p.ib2) + d * Np + cc;
                float a0 = b2[0], a1 = b2[1];
                const float* wp = (pth ? p.tw2 + (size_t)(d * 80) * 512 : p.iw2 + (size_t)(d * 80) * 768) + cc;
                #pragma unroll 16
                for (int k = 0; k < 80; ++k) {
                    float2 w = *reinterpret_cast<const float2*>(wp);
                    float hv = hb[k];
                    a0 += hv * w.x; a1 += hv * w.y;
                    wp += Np;
                }
                sx[2 * c] = a0; sx[2 * c + 1] = a1;
                float* xo = pth ? (p.xt + ((size_t)(d * 36) + blk) * 512 + cc)
                                : (p.xi + ((size_t)(d * 36) + blk) * 768 + cc);
                *reinterpret_cast<float2*>(xo) = make_float2(a0, a1);
            }
            __syncthreads();
        }
    } else {
        float* cx  = smem;
        float* ph  = smem + 512;
        float* hhl = smem + 768;
        const int rr = blk - 36, v = rr / 12, t = rr % 12;
        const float* cs = (v == 0) ? p.cpc : (v == 1) ? p.cpi : p.cpt;
        if (tid < 512) cx[tid] = cs[t * 512 + tid];
        __syncthreads();
        if (tid < 256) {
            const int o = tid & 63, kc = tid >> 6;
            const int path = o >> 5, j = o & 31;
            const float* w = (path ? p.ctw1 : p.ciw1) + (size_t)(kc * 128) * 32 + j;
            float a = 0.f;
            #pragma unroll 8
            for (int i = 0; i < 128; ++i) { a += cx[kc * 128 + i] * (*w); w += 32; }
            ph[kc * 64 + o] = a;
        }
        __syncthreads();
        if (tid < 64) {
            const int path = tid >> 5, j = tid & 31;
            float a = (path ? p.ctb1 : p.cib1)[j];
            #pragma unroll
            for (int kc = 0; kc < 4; ++kc) a += ph[kc * 64 + tid];
            hhl[tid] = gelu_f(a);
        }
        __syncthreads();
        for (int o = tid; o < 1280; o += TPB) {
            if (o < 768) {
                float a = p.cib2[o];
                #pragma unroll
                for (int k = 0; k < 32; ++k) a += hhl[k] * p.ciw2[k * 768 + o];
                p.cimg[rr * 768 + o] = a;
            } else {
                const int oo = o - 768;
                float a = p.ctb2[oo];
                #pragma unroll
                for (int k = 0; k < 32; ++k) a += hhl[32 + k] * p.ctw2[k * 512 + oo];
                p.ctxt[rr * 512 + oo] = a;
            }
        }
    }
}

__global__ __launch_bounds__(256) void emit_kernel(const int* __restrict__ mt,
                                                   const float* __restrict__ xi,
                                                   const float* __restrict__ xt,
                                                   const float* __restrict__ cimg,
                                                   const float* __restrict__ ctxt,
                                                   float* __restrict__ out) {
    constexpr unsigned int C0 = 512u * 24 * 192;
    constexpr unsigned int C1 = 512u * 24 * 128;
    constexpr unsigned int C2 = 11u * 512 * 12 * 192;
    constexpr unsigned int C3 = 11u * 512 * 12 * 128;
    constexpr unsigned int TOT = C0 + C1 + C2 + C3;
    const unsigned int stride = gridDim.x * blockDim.x;
    for (unsigned int c = blockIdx.x * blockDim.x + threadIdx.x; c < TOT; c += stride) {
        const float* src;
        if (c < C0) {
            unsigned int b = c / 4608u, r = c % 4608u;
            unsigned int tok = r / 192u, col = (r % 192u) * 4u;
            int v = mt[b];
            src = (tok < 12u) ? xi + ((size_t)v * 12 + tok) * 768 + col
                              : cimg + ((size_t)v * 12 + (tok - 12u)) * 768 + col;
        } else if (c < C0 + C1) {
            unsigned int cc = c - C0;
            unsigned int b = cc / 3072u, r = cc % 3072u;
            unsigned int tok = r / 128u, col = (r % 128u) * 4u;
            int v = mt[b];
            src = (tok < 12u) ? xt + ((size_t)v * 12 + tok) * 512 + col
                              : ctxt + ((size_t)v * 12 + (tok - 12u)) * 512 + col;
        } else if (c < C0 + C1 + C2) {
            unsigned int cc = c - C0 - C1;
            unsigned int d = cc / 1179648u, r = cc % 1179648u;
            unsigned int b = r / 2304u, rr = r % 2304u;
            unsigned int tok = rr / 192u, col = (rr % 192u) * 4u;
            int v = mt[b];
            src = xi + ((size_t)(d + 1) * 36 + v * 12 + tok) * 768 + col;
        } else {
            unsigned int cc = c - C0 - C1 - C2;
            unsigned int d = cc / 786432u, r = cc % 786432u;
            unsigned int b = r / 1536u, rr = r % 1536u;
            unsigned int tok = rr / 128u, col = (rr % 128u) * 4u;
            int v = mt[b];
            src = xt + ((size_t)(d + 1) * 36 + v * 12 + tok) * 512 + col;
        }
        *reinterpret_cast<float4*>(out + (size_t)c * 4) = *reinterpret_cast<const float4*>(src);
    }
}

extern "C" void kernel_launch(void* const* d_in, const int* in_sizes, int n_in,
                              void* d_out, int out_size, void* d_ws, size_t ws_size,
                              hipStream_t stream) {
    const int* mt = (const int*)d_in[0];
    float* ws = (float*)d_ws;
    P p;
    p.vpc  = (const float*)d_in[1];
    p.vpm  = (const float*)d_in[2];
    p.tpc  = (const float*)d_in[3];
    p.tpm  = (const float*)d_in[4];
    p.cpc  = (const float*)d_in[5];
    p.cpi  = (const float*)d_in[6];
    p.cpt  = (const float*)d_in[7];
    p.lig  = (const float*)d_in[8];
    p.lib  = (const float*)d_in[9];
    p.ltg  = (const float*)d_in[10];
    p.ltb  = (const float*)d_in[11];
    p.iw1  = (const float*)d_in[12];
    p.ib1  = (const float*)d_in[13];
    p.iw2  = (const float*)d_in[14];
    p.ib2  = (const float*)d_in[15];
    p.tw1  = (const float*)d_in[16];
    p.tb1  = (const float*)d_in[17];
    p.tw2  = (const float*)d_in[18];
    p.tb2  = (const float*)d_in[19];
    p.ciw1 = (const float*)d_in[20];
    p.cib1 = (const float*)d_in[21];
    p.ciw2 = (const float*)d_in[22];
    p.cib2 = (const float*)d_in[23];
    p.ctw1 = (const float*)d_in[24];
    p.ctb1 = (const float*)d_in[25];
    p.ctw2 = (const float*)d_in[26];
    p.ctb2 = (const float*)d_in[27];

    const bool packed = (ws_size >= F_END_P * sizeof(float));
    if (packed) {
        p.wp1  = (const u16*)(ws + F_WP1);
        p.wp2  = (const u16*)(ws + F_WP2);
        p.s1   = ws + F_S1;
        p.t1   = ws + F_T1;
        p.xi   = ws + F_XI_P;
        p.xt   = ws + F_XT_P;
        p.cimg = ws + F_CI_P;
        p.ctxt = ws + F_CT_P;
        constexpr u32 N2 = 12u * 80 * 640;
        const int nb = 24 + (N2 + 319) / 320;
        prep_kernel<<<dim3(nb), dim3(320), 0, stream>>>(p, (u16*)(ws + F_WP1), (u32*)(ws + F_WP2),
                                                        ws + F_S1, ws + F_T1);
        chain2_kernel<<<dim3(72), dim3(TPB), 0, stream>>>(p);
    } else {
        p.wp1 = nullptr; p.wp2 = nullptr; p.s1 = nullptr; p.t1 = nullptr;
        p.xi   = ws + F_XI_U;
        p.xt   = ws + F_XT_U;
        p.cimg = ws + F_CI_U;
        p.ctxt = ws + F_CT_U;
        chain_fb_kernel<<<dim3(72), dim3(TPB), 0, stream>>>(p);
    }
    emit_kernel<<<dim3(4096), dim3(256), 0, stream>>>(mt, p.xi, p.xt, p.cimg, p.ctxt, (float*)d_out);
}

// Round 8
// 252.370 us; speedup vs baseline: 1.0634x; 1.0634x over previous
//
#include <hip/hip_runtime.h>

typedef unsigned int u32;
typedef unsigned short u16;

#define TPB 640
#define NSLOT_TOT 180       // 12 depths * 15 slots (10 W1 + 5 W2)
#define SLOT_F32 10240      // 40960 B per slot
#define CHAIN_DYN 92928     // 23222 f32 used

namespace {
// packed ws layout (f32 offsets).  blob = u16[12][307200] = 7,372,800 B = 1,843,200 f32 slots.
// (r6/r7 BUG: F_S1 was 921600 — half the blob's true size; xi/xt writes clobbered weights d>=6.)
constexpr size_t F_BLOB = 0;
constexpr size_t F_S1   = 1843200;    // f32 [12][160]
constexpr size_t F_T1   = 1845120;    // f32 [12][160]
constexpr size_t F_XI   = 1847040;    // f32 [12][36][768]
constexpr size_t F_XT   = 2178816;    // f32 [12][36][512]
constexpr size_t F_CI   = 2400000;    // f32 [36][768]
constexpr size_t F_CT   = 2427648;    // f32 [36][512]
constexpr size_t F_END  = 2446080;    // 9,784,320 B (== r4 footprint, known to fit)
// fallback layout (f32 weights read in place)
constexpr size_t F_XI_U = 0, F_XT_U = 331776, F_CI_U = 552960, F_CT_U = 580608;
}

__device__ __forceinline__ float bflo(u32 u) { return __uint_as_float(u << 16); }
__device__ __forceinline__ float bfhi(u32 u) { return __uint_as_float(u & 0xffff0000u); }
__device__ __forceinline__ float gelu_f(float x) { return 0.5f * x * (1.0f + erff(x * 0.70710678118654752f)); }
__device__ __forceinline__ u16 f2bf(float f) {
    u32 u = __float_as_uint(f);
    u += 0x7fffu + ((u >> 16) & 1u);
    return (u16)(u >> 16);
}

struct P {
    const float *vpc, *vpm, *tpc, *tpm, *cpc, *cpi, *cpt;
    const float *lig, *lib, *ltg, *ltb;
    const float *iw1, *ib1, *iw2, *ib2;
    const float *tw1, *tb1, *tw2, *tb2;
    const float *ciw1, *cib1, *ciw2, *cib2;
    const float *ctw1, *ctb1, *ctw2, *ctb2;
    const u16 *blob;
    const float *s1, *t1;
    float *xi, *xt, *cimg, *ctxt;
};

// ---------------- prep 1: fully-parallel pack (fold LN gamma into W1) ----------------
__global__ __launch_bounds__(256) void prep_pack_kernel(P p, u32* blob32) {
    constexpr u32 N1 = 12u * 1280 * 80;   // W1 u32 pairs
    constexpr u32 N2 = 12u * 80 * 640;    // W2 u32 pairs
    u32 i = blockIdx.x * 256 + threadIdx.x;
    if (i < N1) {
        u32 j2 = i % 80, rem = i / 80;
        u32 k = rem % 1280, d = rem / 1280;
        u32 j0 = 2 * j2;
        const int path = (j0 >= 80);
        const float* W = (path ? p.tw1 : p.iw1) + ((size_t)(d * 1280) + k) * 80 + (j0 - 80 * path);
        float g = (path ? p.ltg : p.lig)[d * 1280 + k];
        float2 v = *reinterpret_cast<const float2*>(W);
        blob32[(size_t)d * 153600 + (size_t)k * 80 + j2] =
            (u32)f2bf(g * v.x) | ((u32)f2bf(g * v.y) << 16);
    } else {
        u32 ii = i - N1;
        if (ii >= N2) return;
        u32 c2 = ii % 640, rem = ii / 640;
        u32 k = rem % 80, d = rem / 80;
        u32 c0 = 2 * c2;
        const float* s = (c0 < 768) ? (p.iw2 + ((size_t)(d * 80) + k) * 768 + c0)
                                    : (p.tw2 + ((size_t)(d * 80) + k) * 512 + (c0 - 768));
        float2 v = *reinterpret_cast<const float2*>(s);
        blob32[(size_t)d * 153600 + 102400 + (size_t)k * 640 + c2] =
            (u32)f2bf(v.x) | ((u32)f2bf(v.y) << 16);
    }
}

// ---------------- prep 2: S1/T1 colsums ----------------
__global__ __launch_bounds__(TPB) void prep_fold_kernel(P p, float* s1o, float* t1o) {
    __shared__ float sA[8][80], sB[8][80];
    const int tid = threadIdx.x;
    const int d = blockIdx.x >> 1, path = blockIdx.x & 1;
    const float* W1 = (path ? p.tw1 : p.iw1) + (size_t)d * 1280 * 80;
    const float* G  = (path ? p.ltg : p.lig) + d * 1280;
    const float* Bb = (path ? p.ltb : p.lib) + d * 1280;
    const int j = tid % 80, kc = tid / 80;    // 8 chunks of 160
    float S = 0.f, T = 0.f;
    for (int k = kc * 160; k < kc * 160 + 160; ++k) {
        float w = W1[(size_t)k * 80 + j];
        S += G[k] * w; T += Bb[k] * w;
    }
    sA[kc][j] = S; sB[kc][j] = T;
    __syncthreads();
    if (tid < 80) {
        float Ss = 0.f, Ts = 0.f;
        #pragma unroll
        for (int q = 0; q < 8; ++q) { Ss += sA[q][tid]; Ts += sB[q][tid]; }
        s1o[d * 160 + path * 80 + tid] = Ss;
        t1o[d * 160 + path * 80 + tid] = Ts + (path ? p.tb1 : p.ib1)[d * 80 + tid];
    }
}

// ---------------- DMA stage: 4 x global_load_lds(16B) per wave, linear copy ----------------
__device__ __forceinline__ void stage_slot(const u16* blob, float* buf, int sigma) {
    const int d = sigma / 15, s = sigma % 15;
    const char* gbase = (const char*)(blob + (size_t)d * 307200
                                      + (s < 10 ? (size_t)s * 20480 : 204800 + (size_t)(s - 10) * 20480));
    char* lbase = (char*)buf;
    const int lane = threadIdx.x & 63, wave = threadIdx.x >> 6;
    #pragma unroll
    for (int r = 0; r < 4; ++r) {
        const int q = r * 10 + wave;
        __builtin_amdgcn_global_load_lds(
            (const __attribute__((address_space(1))) void*)(gbase + q * 1024 + lane * 16),
            (__attribute__((address_space(3))) void*)(lbase + q * 1024), 16, 0, 0);
    }
}

// count-free slot sync: drain ALL vmem (incl. DMA), fence scheduler, barrier
#define SLOT_SYNC do { asm volatile("s_waitcnt vmcnt(0)" ::: "memory"); \
                       __builtin_amdgcn_sched_barrier(0); __syncthreads(); } while (0)

// ---------------- chain: 2-phase DMA double-buffer ----------------
__global__ __launch_bounds__(TPB) void chain4_kernel(P p) {
    extern __shared__ float smem[];
    float* buf0 = smem;             // [10240]
    float* buf1 = smem + 10240;     // [10240]
    float* sx   = smem + 20480;     // [1280]
    float* part = smem + 21760;     // [8][160]
    float* hh   = smem + 23040;     // [160]
    float* redA = smem + 23200;     // [10]
    float* redB = smem + 23210;     // [10]
    float* st   = smem + 23220;     // [2]

    const int tid = threadIdx.x, blk = blockIdx.x;

    if (blk < 36) {
        const int v = blk / 12, t = blk % 12;
        stage_slot(p.blob, buf0, 0);
        const float* is = (v == 2) ? p.vpm : p.vpc;
        const float* ts = (v == 1) ? p.tpm : p.tpc;
        for (int k = tid; k < 768; k += TPB) sx[k] = is[t * 768 + k];
        if (tid < 512) sx[768 + tid] = ts[t * 512 + tid];
        SLOT_SYNC;            // slot 0 landed; sx ready
        int cur = 0;
        const int jp = tid % 80, kc = tid / 80;

        for (int d = 0; d < 12; ++d) {
            // ---- LN stats over sx ----
            {
                float x0 = sx[tid], x1 = sx[tid + 640];
                float s = x0 + x1, s2 = x0 * x0 + x1 * x1;
                #pragma unroll
                for (int off = 32; off > 0; off >>= 1) { s += __shfl_down(s, off); s2 += __shfl_down(s2, off); }
                if ((tid & 63) == 0) { redA[tid >> 6] = s; redB[tid >> 6] = s2; }
            }
            __syncthreads();
            if (tid == 0) {
                float S = 0.f, S2 = 0.f;
                #pragma unroll
                for (int w = 0; w < 10; ++w) { S += redA[w]; S2 += redB[w]; }
                float m = S * (1.0f / 1280.0f);
                float var = S2 * (1.0f / 1280.0f) - m * m;
                st[0] = m; st[1] = rsqrtf(var + 1e-5f);
            }
            float a0 = 0.f, a1 = 0.f, b0 = 0.f, b1 = 0.f;
            // ---- W1 slots: 10 x 128 K-rows ----
            for (int s = 0; s < 10; ++s) {
                const int sig = d * 15 + s;
                if (sig + 1 < NSLOT_TOT) stage_slot(p.blob, cur ? buf0 : buf1, sig + 1);
                const u32* wp = (const u32*)(cur ? buf1 : buf0) + kc * 1280 + jp;
                const float* xs = sx + s * 128 + kc * 16;
                #pragma unroll
                for (int i = 0; i < 16; ++i) {
                    u32 w = wp[i * 80];
                    float xv = xs[i];
                    a0 += xv * bflo(w); a1 += xv * bfhi(w);
                }
                if (s == 9) { part[kc * 160 + 2 * jp] = a0; part[kc * 160 + 2 * jp + 1] = a1; }
                SLOT_SYNC; cur ^= 1;
            }
            if (tid < 160) {
                float y = 0.f;
                #pragma unroll
                for (int q = 0; q < 8; ++q) y += part[q * 160 + tid];
                const float m = st[0], rs = st[1];
                hh[tid] = gelu_f(rs * y - m * rs * p.s1[d * 160 + tid] + p.t1[d * 160 + tid]);
            }
            __syncthreads();   // hh visible
            // ---- W2 slots: 5 x 16 K-rows ----
            for (int s = 10; s < 15; ++s) {
                const int sig = d * 15 + s;
                if (sig + 1 < NSLOT_TOT) stage_slot(p.blob, cur ? buf0 : buf1, sig + 1);
                const u32* wq = (const u32*)(cur ? buf1 : buf0) + tid;
                const float* hb = hh + ((tid >= 384) ? 80 : 0) + (s - 10) * 16;
                #pragma unroll
                for (int i = 0; i < 16; ++i) {
                    u32 w = wq[i * 640];
                    float hv = hb[i];
                    b0 += hv * bflo(w); b1 += hv * bfhi(w);
                }
                SLOT_SYNC; cur ^= 1;
            }
            // ---- combine: bias + write x(d) ----
            {
                const int c0 = 2 * tid;
                const int pth = (c0 >= 768);
                const int cc = c0 - 768 * pth;
                const int Np = pth ? 512 : 768;
                const float* bb = (pth ? p.tb2 : p.ib2) + d * Np + cc;
                float o0 = b0 + bb[0], o1 = b1 + bb[1];
                sx[c0] = o0; sx[c0 + 1] = o1;
                float* xo = pth ? (p.xt + ((size_t)(d * 36) + blk) * 512 + cc)
                                : (p.xi + ((size_t)(d * 36) + blk) * 768 + cc);
                *reinterpret_cast<float2*>(xo) = make_float2(o0, o1);
            }
            __syncthreads();
        }
    } else {
        // ---- common-prompt MLPs ----
        float* cx  = smem;         // [512]
        float* ph  = smem + 512;   // [4][64]
        float* hhl = smem + 768;   // [64]
        const int rr = blk - 36, v = rr / 12, t = rr % 12;
        const float* cs = (v == 0) ? p.cpc : (v == 1) ? p.cpi : p.cpt;
        if (tid < 512) cx[tid] = cs[t * 512 + tid];
        __syncthreads();
        if (tid < 256) {
            const int o = tid & 63, kcq = tid >> 6;
            const int path = o >> 5, j = o & 31;
            const float* w = (path ? p.ctw1 : p.ciw1) + (size_t)(kcq * 128) * 32 + j;
            float a = 0.f;
            #pragma unroll 8
            for (int i = 0; i < 128; ++i) { a += cx[kcq * 128 + i] * (*w); w += 32; }
            ph[kcq * 64 + o] = a;
        }
        __syncthreads();
        if (tid < 64) {
            const int path = tid >> 5, j = tid & 31;
            float a = (path ? p.ctb1 : p.cib1)[j];
            #pragma unroll
            for (int q = 0; q < 4; ++q) a += ph[q * 64 + tid];
            hhl[tid] = gelu_f(a);
        }
        __syncthreads();
        for (int o = tid; o < 1280; o += TPB) {
            if (o < 768) {
                float a = p.cib2[o];
                #pragma unroll
                for (int k = 0; k < 32; ++k) a += hhl[k] * p.ciw2[k * 768 + o];
                p.cimg[rr * 768 + o] = a;
            } else {
                const int oo = o - 768;
                float a = p.ctb2[oo];
                #pragma unroll
                for (int k = 0; k < 32; ++k) a += hhl[32 + k] * p.ctw2[k * 512 + oo];
                p.ctxt[rr * 512 + oo] = a;
            }
        }
    }
}

// ---------------- fallback chain (f32 weights in place; round-4 proven) ----------------
__global__ __launch_bounds__(TPB) void chain_fb_kernel(P p) {
    __shared__ float smem[6592];
    float* sx   = smem;
    float* xln0 = smem + 1280;
    float* xln1 = smem + 2560;
    float* part = smem + 3840;
    float* hh   = smem + 6400;
    float* redA = smem + 6560;
    float* redB = smem + 6570;
    float* st   = smem + 6580;
    const int tid = threadIdx.x, blk = blockIdx.x;
    if (blk < 36) {
        const int v = blk / 12, t = blk % 12;
        const float* is = (v == 2) ? p.vpm : p.vpc;
        const float* ts = (v == 1) ? p.tpm : p.tpc;
        if (tid < 512) sx[768 + tid] = ts[t * 512 + tid];
        for (int k = tid; k < 768; k += TPB) sx[k] = is[t * 768 + k];
        __syncthreads();
        for (int d = 0; d < 12; ++d) {
            {
                float x0 = sx[tid], x1 = sx[tid + 640];
                float s = x0 + x1, s2 = x0 * x0 + x1 * x1;
                #pragma unroll
                for (int off = 32; off > 0; off >>= 1) { s += __shfl_down(s, off); s2 += __shfl_down(s2, off); }
                if ((tid & 63) == 0) { redA[tid >> 6] = s; redB[tid >> 6] = s2; }
            }
            __syncthreads();
            if (tid == 0) {
                float S = 0.f, S2 = 0.f;
                #pragma unroll
                for (int w = 0; w < 10; ++w) { S += redA[w]; S2 += redB[w]; }
                float m = S * (1.0f / 1280.0f);
                float var = S2 * (1.0f / 1280.0f) - m * m;
                st[0] = m; st[1] = rsqrtf(var + 1e-5f);
            }
            __syncthreads();
            const float m = st[0], rs = st[1];
            #pragma unroll
            for (int q = 0; q < 2; ++q) {
                const int k = tid + 640 * q;
                float xc = (sx[k] - m) * rs;
                xln0[k] = xc * p.lig[d * 1280 + k] + p.lib[d * 1280 + k];
                xln1[k] = xc * p.ltg[d * 1280 + k] + p.ltb[d * 1280 + k];
            }
            __syncthreads();
            {
                const int g = tid % 40, kcq = tid / 40;
                const int j0 = 4 * g;
                const float* xl = (j0 >= 80) ? xln1 : xln0;
                const int k0 = kcq * 80;
                float a0 = 0.f, a1 = 0.f, a2 = 0.f, a3 = 0.f;
                const float* wp = (j0 < 80) ? (p.iw1 + ((size_t)(d * 1280) + k0) * 80 + j0)
                                            : (p.tw1 + ((size_t)(d * 1280) + k0) * 80 + (j0 - 80));
                #pragma unroll 8
                for (int i = 0; i < 80; ++i) {
                    float4 w = *reinterpret_cast<const float4*>(wp);
                    float xv = xl[k0 + i];
                    a0 += xv * w.x; a1 += xv * w.y; a2 += xv * w.z; a3 += xv * w.w;
                    wp += 80;
                }
                *reinterpret_cast<float4*>(part + kcq * 160 + j0) = make_float4(a0, a1, a2, a3);
            }
            __syncthreads();
            if (tid < 160) {
                const int path = tid >= 80, j = tid - 80 * path;
                float a = (path ? p.tb1 : p.ib1)[d * 80 + j];
                #pragma unroll
                for (int q = 0; q < 16; ++q) a += part[q * 160 + tid];
                hh[tid] = gelu_f(a);
            }
            __syncthreads();
            {
                const int c = tid;
                const int pth = (c >= 384);
                const int cc = 2 * c - 768 * pth;
                const float* hb = hh + 80 * pth;
                const int Np = pth ? 512 : 768;
                const float* b2 = (pth ? p.tb2 : p.ib2) + d * Np + cc;
                float a0 = b2[0], a1 = b2[1];
                const float* wp = (pth ? p.tw2 + (size_t)(d * 80) * 512 : p.iw2 + (size_t)(d * 80) * 768) + cc;
                #pragma unroll 16
                for (int k = 0; k < 80; ++k) {
                    float2 w = *reinterpret_cast<const float2*>(wp);
                    float hv = hb[k];
                    a0 += hv * w.x; a1 += hv * w.y;
                    wp += Np;
                }
                sx[2 * c] = a0; sx[2 * c + 1] = a1;
                float* xo = pth ? (p.xt + ((size_t)(d * 36) + blk) * 512 + cc)
                                : (p.xi + ((size_t)(d * 36) + blk) * 768 + cc);
                *reinterpret_cast<float2*>(xo) = make_float2(a0, a1);
            }
            __syncthreads();
        }
    } else {
        float* cx  = smem;
        float* ph  = smem + 512;
        float* hhl = smem + 768;
        const int rr = blk - 36, v = rr / 12, t = rr % 12;
        const float* cs = (v == 0) ? p.cpc : (v == 1) ? p.cpi : p.cpt;
        if (tid < 512) cx[tid] = cs[t * 512 + tid];
        __syncthreads();
        if (tid < 256) {
            const int o = tid & 63, kcq = tid >> 6;
            const int path = o >> 5, j = o & 31;
            const float* w = (path ? p.ctw1 : p.ciw1) + (size_t)(kcq * 128) * 32 + j;
            float a = 0.f;
            #pragma unroll 8
            for (int i = 0; i < 128; ++i) { a += cx[kcq * 128 + i] * (*w); w += 32; }
            ph[kcq * 64 + o] = a;
        }
        __syncthreads();
        if (tid < 64) {
            const int path = tid >> 5, j = tid & 31;
            float a = (path ? p.ctb1 : p.cib1)[j];
            #pragma unroll
            for (int q = 0; q < 4; ++q) a += ph[q * 64 + tid];
            hhl[tid] = gelu_f(a);
        }
        __syncthreads();
        for (int o = tid; o < 1280; o += TPB) {
            if (o < 768) {
                float a = p.cib2[o];
                #pragma unroll
                for (int k = 0; k < 32; ++k) a += hhl[k] * p.ciw2[k * 768 + o];
                p.cimg[rr * 768 + o] = a;
            } else {
                const int oo = o - 768;
                float a = p.ctb2[oo];
                #pragma unroll
                for (int k = 0; k < 32; ++k) a += hhl[32 + k] * p.ctw2[k * 512 + oo];
                p.ctxt[rr * 512 + oo] = a;
            }
        }
    }
}

// ---------------- emit: broadcast/gather to f32 outputs ----------------
__global__ __launch_bounds__(256) void emit_kernel(const int* __restrict__ mt,
                                                   const float* __restrict__ xi,
                                                   const float* __restrict__ xt,
                                                   const float* __restrict__ cimg,
                                                   const float* __restrict__ ctxt,
                                                   float* __restrict__ out) {
    constexpr unsigned int C0 = 512u * 24 * 192;
    constexpr unsigned int C1 = 512u * 24 * 128;
    constexpr unsigned int C2 = 11u * 512 * 12 * 192;
    constexpr unsigned int C3 = 11u * 512 * 12 * 128;
    constexpr unsigned int TOT = C0 + C1 + C2 + C3;
    const unsigned int stride = gridDim.x * blockDim.x;
    for (unsigned int c = blockIdx.x * blockDim.x + threadIdx.x; c < TOT; c += stride) {
        const float* src;
        if (c < C0) {
            unsigned int b = c / 4608u, r = c % 4608u;
            unsigned int tok = r / 192u, col = (r % 192u) * 4u;
            int v = mt[b];
            src = (tok < 12u) ? xi + ((size_t)v * 12 + tok) * 768 + col
                              : cimg + ((size_t)v * 12 + (tok - 12u)) * 768 + col;
        } else if (c < C0 + C1) {
            unsigned int cc = c - C0;
            unsigned int b = cc / 3072u, r = cc % 3072u;
            unsigned int tok = r / 128u, col = (r % 128u) * 4u;
            int v = mt[b];
            src = (tok < 12u) ? xt + ((size_t)v * 12 + tok) * 512 + col
                              : ctxt + ((size_t)v * 12 + (tok - 12u)) * 512 + col;
        } else if (c < C0 + C1 + C2) {
            unsigned int cc = c - C0 - C1;
            unsigned int d = cc / 1179648u, r = cc % 1179648u;
            unsigned int b = r / 2304u, rr = r % 2304u;
            unsigned int tok = rr / 192u, col = (rr % 192u) * 4u;
            int v = mt[b];
            src = xi + ((size_t)(d + 1) * 36 + v * 12 + tok) * 768 + col;
        } else {
            unsigned int cc = c - C0 - C1 - C2;
            unsigned int d = cc / 786432u, r = cc % 786432u;
            unsigned int b = r / 1536u, rr = r % 1536u;
            unsigned int tok = rr / 128u, col = (rr % 128u) * 4u;
            int v = mt[b];
            src = xt + ((size_t)(d + 1) * 36 + v * 12 + tok) * 512 + col;
        }
        *reinterpret_cast<float4*>(out + (size_t)c * 4) = *reinterpret_cast<const float4*>(src);
    }
}

extern "C" void kernel_launch(void* const* d_in, const int* in_sizes, int n_in,
                              void* d_out, int out_size, void* d_ws, size_t ws_size,
                              hipStream_t stream) {
    const int* mt = (const int*)d_in[0];
    float* ws = (float*)d_ws;
    P p;
    p.vpc  = (const float*)d_in[1];
    p.vpm  = (const float*)d_in[2];
    p.tpc  = (const float*)d_in[3];
    p.tpm  = (const float*)d_in[4];
    p.cpc  = (const float*)d_in[5];
    p.cpi  = (const float*)d_in[6];
    p.cpt  = (const float*)d_in[7];
    p.lig  = (const float*)d_in[8];
    p.lib  = (const float*)d_in[9];
    p.ltg  = (const float*)d_in[10];
    p.ltb  = (const float*)d_in[11];
    p.iw1  = (const float*)d_in[12];
    p.ib1  = (const float*)d_in[13];
    p.iw2  = (const float*)d_in[14];
    p.ib2  = (const float*)d_in[15];
    p.tw1  = (const float*)d_in[16];
    p.tb1  = (const float*)d_in[17];
    p.tw2  = (const float*)d_in[18];
    p.tb2  = (const float*)d_in[19];
    p.ciw1 = (const float*)d_in[20];
    p.cib1 = (const float*)d_in[21];
    p.ciw2 = (const float*)d_in[22];
    p.cib2 = (const float*)d_in[23];
    p.ctw1 = (const float*)d_in[24];
    p.ctb1 = (const float*)d_in[25];
    p.ctw2 = (const float*)d_in[26];
    p.ctb2 = (const float*)d_in[27];

    const bool packed = (ws_size >= F_END * sizeof(float));
    if (packed) {
        p.blob = (const u16*)(ws + F_BLOB);
        p.s1   = ws + F_S1;
        p.t1   = ws + F_T1;
        p.xi   = ws + F_XI;
        p.xt   = ws + F_XT;
        p.cimg = ws + F_CI;
        p.ctxt = ws + F_CT;
        constexpr u32 NPAIR = 12u * 1280 * 80 + 12u * 80 * 640;
        prep_pack_kernel<<<dim3((NPAIR + 255) / 256), dim3(256), 0, stream>>>(p, (u32*)(ws + F_BLOB));
        prep_fold_kernel<<<dim3(24), dim3(TPB), 0, stream>>>(p, ws + F_S1, ws + F_T1);
        hipFuncSetAttribute((const void*)chain4_kernel,
                            hipFuncAttributeMaxDynamicSharedMemorySize, CHAIN_DYN);
        chain4_kernel<<<dim3(72), dim3(TPB), CHAIN_DYN, stream>>>(p);
    } else {
        p.blob = nullptr; p.s1 = nullptr; p.t1 = nullptr;
        p.xi   = ws + F_XI_U;
        p.xt   = ws + F_XT_U;
        p.cimg = ws + F_CI_U;
        p.ctxt = ws + F_CT_U;
        chain_fb_kernel<<<dim3(72), dim3(TPB), 0, stream>>>(p);
    }
    emit_kernel<<<dim3(4096), dim3(256), 0, stream>>>(mt, p.xi, p.xt, p.cimg, p.ctxt, (float*)d_out);
}